// Round 1
// baseline (1508.821 us; speedup 1.0000x reference)
//
#include <hip/hip_runtime.h>
#include <hip/hip_bf16.h>
#include <math.h>

// Problem constants (fixed by the reference):
//   N=100000, E=3200000, R=9, G=768, H1=64, H2=32, C=4
// Pipeline:
//   h1 = x@Wp + bp                                  [N,64]
//   hw = h1 @ [W_rel(9) | W_root] (concat cols)     [N,320]
//   CSR bucket edges by dst; cnt per (r,dst)
//   h2 = relu( sum_e hw[src][r]/cnt[r,dst] + hw[dst][root] + b_rgcn )
//   qkvs = h2 @ [Wq|Wk|Wv|Wskip] + [bq|bk|bv|bskip] [N,128]
//   per-dst online softmax over edges -> attn; h3 = relu(attn + skip + bskip)
//   out = h3 @ Wf + bf  (fused into attention epilogue)

#define GDIM 768
#define H1D 64
#define H2D 32
#define NREL 9

// ---------------- small utility kernels ----------------

__global__ void zero_ints(int* __restrict__ p, int count) {
  for (int i = blockIdx.x * blockDim.x + threadIdx.x; i < count;
       i += gridDim.x * blockDim.x)
    p[i] = 0;
}

// Wcat[k][m], m = r*32+o for r<9 -> W_rel[r][k][o]; m in [288,320) -> W_root[k][o]
__global__ void build_wcat(const float* __restrict__ W_rel,
                           const float* __restrict__ W_root,
                           float* __restrict__ Wcat) {
  int i = blockIdx.x * blockDim.x + threadIdx.x;
  if (i >= H1D * 320) return;
  int k = i / 320, m = i % 320;
  float v;
  if (m < NREL * H2D) {
    int r = m >> 5, o = m & 31;
    v = W_rel[(size_t)r * H1D * H2D + k * H2D + o];
  } else {
    v = W_root[k * H2D + (m - NREL * H2D)];
  }
  Wcat[i] = v;
}

// Wqkvs[32][128] = concat cols of Wq,Wk,Wv,Wskip ; bqkvs[128]
__global__ void build_wqkvs(const float* __restrict__ Wq, const float* __restrict__ Wk,
                            const float* __restrict__ Wv, const float* __restrict__ Ws,
                            const float* __restrict__ bq, const float* __restrict__ bk,
                            const float* __restrict__ bv, const float* __restrict__ bs,
                            float* __restrict__ Wqkvs, float* __restrict__ bqkvs) {
  int i = blockIdx.x * blockDim.x + threadIdx.x;
  if (i < H2D * 128) {
    int k = i / 128, c = i % 128;
    int sel = c >> 5, o = c & 31;
    const float* W = (sel == 0) ? Wq : (sel == 1) ? Wk : (sel == 2) ? Wv : Ws;
    Wqkvs[i] = W[k * H2D + o];
  }
  if (i < 128) {
    int sel = i >> 5, o = i & 31;
    const float* b = (sel == 0) ? bq : (sel == 1) ? bk : (sel == 2) ? bv : bs;
    bqkvs[i] = b[o];
  }
}

// ---------------- generic fp32 tiled GEMM: C = A[MxK] @ B[KxN] (+bias) ----------------
// K % 16 == 0, N % 64 == 0. Tile 64x64, 256 threads, 4x4 per thread.

template <bool BIAS>
__global__ __launch_bounds__(256) void gemm_tile(
    const float* __restrict__ A, const float* __restrict__ B,
    const float* __restrict__ bias, float* __restrict__ C, int M, int K, int N) {
  __shared__ float As[64][17];
  __shared__ float Bs[16][68];
  const int m0 = blockIdx.x * 64;
  const int n0 = blockIdx.y * 64;
  const int tid = threadIdx.x;
  const int tr = tid >> 4, tc = tid & 15;

  float acc[4][4] = {{0.f}};

  for (int kk = 0; kk < K; kk += 16) {
    // stage A tile (64 rows x 16 k)
    {
      int ar = tid >> 2;
      int ac = (tid & 3) * 4;
      float4 av = make_float4(0.f, 0.f, 0.f, 0.f);
      if (m0 + ar < M)
        av = *(const float4*)(A + (size_t)(m0 + ar) * K + kk + ac);
      As[ar][ac + 0] = av.x; As[ar][ac + 1] = av.y;
      As[ar][ac + 2] = av.z; As[ar][ac + 3] = av.w;
    }
    // stage B tile (16 k x 64 cols)
    {
      int br = tid >> 4;
      int bc = (tid & 15) * 4;
      float4 bv = *(const float4*)(B + (size_t)(kk + br) * N + n0 + bc);
      *(float4*)(&Bs[br][bc]) = bv;
    }
    __syncthreads();
#pragma unroll
    for (int k = 0; k < 16; ++k) {
      float a0 = As[tr * 4 + 0][k];
      float a1 = As[tr * 4 + 1][k];
      float a2 = As[tr * 4 + 2][k];
      float a3 = As[tr * 4 + 3][k];
      float4 b = *(const float4*)(&Bs[k][tc * 4]);
      acc[0][0] += a0 * b.x; acc[0][1] += a0 * b.y; acc[0][2] += a0 * b.z; acc[0][3] += a0 * b.w;
      acc[1][0] += a1 * b.x; acc[1][1] += a1 * b.y; acc[1][2] += a1 * b.z; acc[1][3] += a1 * b.w;
      acc[2][0] += a2 * b.x; acc[2][1] += a2 * b.y; acc[2][2] += a2 * b.z; acc[2][3] += a2 * b.w;
      acc[3][0] += a3 * b.x; acc[3][1] += a3 * b.y; acc[3][2] += a3 * b.z; acc[3][3] += a3 * b.w;
    }
    __syncthreads();
  }

#pragma unroll
  for (int i = 0; i < 4; ++i) {
    int row = m0 + tr * 4 + i;
    if (row < M) {
      int col = n0 + tc * 4;
      float4 v;
      v.x = acc[i][0]; v.y = acc[i][1]; v.z = acc[i][2]; v.w = acc[i][3];
      if (BIAS) {
        v.x += bias[col + 0]; v.y += bias[col + 1];
        v.z += bias[col + 2]; v.w += bias[col + 3];
      }
      *(float4*)(C + (size_t)row * N + col) = v;
    }
  }
}

// ---------------- edge counting / CSR build ----------------

__global__ void count_edges(const int* __restrict__ ei, const int* __restrict__ et,
                            int* __restrict__ deg, int* __restrict__ cnt_rd,
                            int e, int n) {
  int i = blockIdx.x * blockDim.x + threadIdx.x;
  if (i >= e) return;
  int dst = ei[e + i];
  int t = et[i];
  atomicAdd(&deg[dst], 1);
  atomicAdd(&cnt_rd[t * n + dst], 1);
}

// convert counts -> 1/max(cnt,1), in place (int -> float bitcast)
__global__ void invert_counts(int* __restrict__ cnt_rd, int count) {
  for (int i = blockIdx.x * blockDim.x + threadIdx.x; i < count;
       i += gridDim.x * blockDim.x) {
    int c = cnt_rd[i];
    if (c < 1) c = 1;
    float inv = 1.0f / (float)c;
    ((float*)cnt_rd)[i] = inv;
  }
}

__global__ void scan_block_sums(const int* __restrict__ deg, int* __restrict__ partials,
                                int n) {
  int i = blockIdx.x * 256 + threadIdx.x;
  int v = (i < n) ? deg[i] : 0;
#pragma unroll
  for (int off = 32; off > 0; off >>= 1) v += __shfl_down(v, off, 64);
  __shared__ int wsum[4];
  if ((threadIdx.x & 63) == 0) wsum[threadIdx.x >> 6] = v;
  __syncthreads();
  if (threadIdx.x == 0)
    partials[blockIdx.x] = wsum[0] + wsum[1] + wsum[2] + wsum[3];
}

// single block of 1024, nb <= 1024
__global__ void scan_partials(const int* __restrict__ partials,
                              int* __restrict__ blockoff, int nb) {
  __shared__ int s[1024];
  int t = threadIdx.x;
  int v = (t < nb) ? partials[t] : 0;
  s[t] = v;
  __syncthreads();
  for (int off = 1; off < 1024; off <<= 1) {
    int add = (t >= off) ? s[t - off] : 0;
    __syncthreads();
    s[t] += add;
    __syncthreads();
  }
  blockoff[t] = s[t] - v;  // exclusive
}

__global__ void scan_final(const int* __restrict__ deg, const int* __restrict__ blockoff,
                           int* __restrict__ rowptr, int* __restrict__ cursor, int n) {
  int i = blockIdx.x * 256 + threadIdx.x;
  int lane = threadIdx.x & 63;
  int v = (i < n) ? deg[i] : 0;
  int incl = v;
#pragma unroll
  for (int off = 1; off < 64; off <<= 1) {
    int u = __shfl_up(incl, off, 64);
    if (lane >= off) incl += u;
  }
  __shared__ int wsum[4];
  if (lane == 63) wsum[threadIdx.x >> 6] = incl;
  __syncthreads();
  int w = threadIdx.x >> 6;
  int woff = 0;
  for (int j = 0; j < w; ++j) woff += wsum[j];
  int excl = incl - v + woff + blockoff[blockIdx.x];
  if (i < n) {
    rowptr[i] = excl;
    cursor[i] = excl;
  }
}

__global__ void scatter_edges(const int* __restrict__ ei, const int* __restrict__ et,
                              int* __restrict__ cursor, unsigned* __restrict__ csr,
                              int e) {
  int i = blockIdx.x * blockDim.x + threadIdx.x;
  if (i >= e) return;
  int src = ei[i];
  int dst = ei[e + i];
  int t = et[i];
  int pos = atomicAdd(&cursor[dst], 1);
  csr[pos] = (unsigned)src | ((unsigned)t << 20);
}

// ---------------- RGCN aggregate: one wave per dst ----------------
// acc[o] = sum_e hw[src_e][r_e*32+o] * inv_cnt[r_e,dst]; h2 = relu(acc + root + b)

__global__ __launch_bounds__(256) void rgcn_agg(
    const unsigned* __restrict__ csr, const int* __restrict__ rowptr,
    const int* __restrict__ deg, const float* __restrict__ inv_rd,
    const float* __restrict__ hw, const float* __restrict__ b_rgcn,
    float* __restrict__ h2, int n) {
  int wid = (blockIdx.x * 256 + threadIdx.x) >> 6;
  if (wid >= n) return;
  int lane = threadIdx.x & 63;
  int half = lane >> 5, o = lane & 31;
  int dst = wid;
  int start = rowptr[dst];
  int cnt = deg[dst];
  float acc = 0.f;
  for (int i = half; i < cnt; i += 2) {
    unsigned p = csr[start + i];
    int src = p & 0xFFFFF;
    int r = p >> 20;
    float norm = inv_rd[r * n + dst];
    acc += hw[(size_t)src * 320 + r * 32 + o] * norm;
  }
  acc += __shfl_xor(acc, 32, 64);
  float root = hw[(size_t)dst * 320 + NREL * 32 + o] + b_rgcn[o];
  float v = acc + root;
  v = v > 0.f ? v : 0.f;
  if (half == 0) h2[(size_t)dst * 32 + o] = v;
}

// ---------------- attention + skip + classifier: one wave per dst ----------------

__global__ __launch_bounds__(256) void attn_out(
    const unsigned* __restrict__ csr, const int* __restrict__ rowptr,
    const int* __restrict__ deg, const float* __restrict__ qkvs,
    const float* __restrict__ bskip, const float* __restrict__ Wf,
    const float* __restrict__ bf, float* __restrict__ out, int n) {
  int wid = (blockIdx.x * 256 + threadIdx.x) >> 6;
  if (wid >= n) return;
  int lane = threadIdx.x & 63;
  int half = lane >> 5, o = lane & 31;
  int dst = wid;
  const float scale = 0.1767766952966369f;  // 1/sqrt(32)

  float qv = qkvs[(size_t)dst * 128 + o];
  int start = rowptr[dst];
  int cnt = deg[dst];

  float m = -INFINITY, den = 0.f, acc = 0.f;
  for (int i = half; i < cnt; i += 2) {
    unsigned p = csr[start + i];
    int src = p & 0xFFFFF;
    float kv = qkvs[(size_t)src * 128 + 32 + o];
    float vv = qkvs[(size_t)src * 128 + 64 + o];
    float prod = qv * kv;
    prod += __shfl_xor(prod, 1, 64);
    prod += __shfl_xor(prod, 2, 64);
    prod += __shfl_xor(prod, 4, 64);
    prod += __shfl_xor(prod, 8, 64);
    prod += __shfl_xor(prod, 16, 64);
    float logit = prod * scale;
    float nm = fmaxf(m, logit);
    float c = __expf(m - nm);      // m=-inf -> 0
    float pp = __expf(logit - nm);
    den = den * c + pp;
    acc = acc * c + pp * vv;
    m = nm;
  }
  // merge the two halves' online-softmax states
  float mo = __shfl_xor(m, 32, 64);
  float nm = fmaxf(m, mo);
  float c = (m > -INFINITY) ? __expf(m - nm) : 0.f;
  float sden = den * c, sacc = acc * c;
  sden += __shfl_xor(sden, 32, 64);
  sacc += __shfl_xor(sacc, 32, 64);
  float attn = (sden > 0.f) ? (sacc / sden) : 0.f;

  float sv = qkvs[(size_t)dst * 128 + 96 + o] + bskip[o];
  float h3 = attn + sv;
  h3 = h3 > 0.f ? h3 : 0.f;

  // classifier: out[dst][c] = sum_o h3[o]*Wf[o][c] + bf[c]
#pragma unroll
  for (int cidx = 0; cidx < 4; ++cidx) {
    float t = h3 * Wf[o * 4 + cidx];
    t += __shfl_xor(t, 1, 64);
    t += __shfl_xor(t, 2, 64);
    t += __shfl_xor(t, 4, 64);
    t += __shfl_xor(t, 8, 64);
    t += __shfl_xor(t, 16, 64);
    if (lane == 0) out[(size_t)dst * 4 + cidx] = t + bf[cidx];
  }
}

// ---------------- launch ----------------

extern "C" void kernel_launch(void* const* d_in, const int* in_sizes, int n_in,
                              void* d_out, int out_size, void* d_ws, size_t ws_size,
                              hipStream_t stream) {
  const float* x      = (const float*)d_in[0];
  // d_in[1] = lengths (unused by the reference)
  const int*   ei     = (const int*)d_in[2];
  const int*   et     = (const int*)d_in[3];
  const float* Wp     = (const float*)d_in[4];
  const float* bp     = (const float*)d_in[5];
  const float* W_rel  = (const float*)d_in[6];
  const float* W_root = (const float*)d_in[7];
  const float* b_rgcn = (const float*)d_in[8];
  const float* Wq     = (const float*)d_in[9];
  const float* bq     = (const float*)d_in[10];
  const float* Wk     = (const float*)d_in[11];
  const float* bk     = (const float*)d_in[12];
  const float* Wv     = (const float*)d_in[13];
  const float* bv     = (const float*)d_in[14];
  const float* Wskip  = (const float*)d_in[15];
  const float* bskip  = (const float*)d_in[16];
  const float* Wf     = (const float*)d_in[17];
  const float* bf     = (const float*)d_in[18];
  float* out = (float*)d_out;

  const int n = in_sizes[0] / GDIM;      // 100000
  const int e = in_sizes[3];             // 3200000

  // workspace layout (floats)
  float* ws = (float*)d_ws;
  size_t off = 0;
  float* h1    = ws + off; off += (size_t)n * H1D;        // 6.4M
  float* hw    = ws + off; off += (size_t)n * 320;        // 32M
  float* h2    = ws + off; off += (size_t)n * H2D;        // 3.2M
  float* qkvs  = ws + off; off += (size_t)n * 128;        // 12.8M
  float* Wcat  = ws + off; off += (size_t)H1D * 320;
  float* Wqkvs = ws + off; off += (size_t)H2D * 128;
  float* bqkvs = ws + off; off += 128;
  int* deg     = (int*)(ws + off); off += n;
  int* cnt_rd  = (int*)(ws + off); off += (size_t)NREL * n;   // becomes inv_rd (float)
  int* rowptr  = (int*)(ws + off); off += n;
  int* cursor  = (int*)(ws + off); off += n;
  int* partials= (int*)(ws + off); off += 1024;
  int* blockoff= (int*)(ws + off); off += 1024;
  unsigned* csr= (unsigned*)(ws + off); off += e;

  const int nb = (n + 255) / 256;  // scan blocks (391)

  // 1. zero deg + cnt_rd (contiguous)
  zero_ints<<<2048, 256, 0, stream>>>(deg, n + NREL * n);
  // 2. build concatenated weights
  build_wcat<<<(H1D * 320 + 255) / 256, 256, 0, stream>>>(W_rel, W_root, Wcat);
  build_wqkvs<<<(H2D * 128 + 255) / 256, 256, 0, stream>>>(
      Wq, Wk, Wv, Wskip, bq, bk, bv, bskip, Wqkvs, bqkvs);
  // 3. h1 = x@Wp + bp
  {
    dim3 g((n + 63) / 64, H1D / 64);
    gemm_tile<true><<<g, 256, 0, stream>>>(x, Wp, bp, h1, n, GDIM, H1D);
  }
  // 4. edge counting
  count_edges<<<(e + 255) / 256, 256, 0, stream>>>(ei, et, deg, cnt_rd, e, n);
  invert_counts<<<2048, 256, 0, stream>>>(cnt_rd, NREL * n);
  // 5-7. exclusive scan of deg -> rowptr, cursor
  scan_block_sums<<<nb, 256, 0, stream>>>(deg, partials, n);
  scan_partials<<<1, 1024, 0, stream>>>(partials, blockoff, nb);
  scan_final<<<nb, 256, 0, stream>>>(deg, blockoff, rowptr, cursor, n);
  // 8. scatter edges into CSR
  scatter_edges<<<(e + 255) / 256, 256, 0, stream>>>(ei, et, cursor, csr, e);
  // 9. hw = h1 @ Wcat  [n x 320]
  {
    dim3 g((n + 63) / 64, 320 / 64);
    gemm_tile<false><<<g, 256, 0, stream>>>(h1, Wcat, nullptr, hw, n, H1D, 320);
  }
  // 10. RGCN aggregate -> h2
  {
    int blocks = (n * 64 + 255) / 256;
    rgcn_agg<<<blocks, 256, 0, stream>>>(csr, rowptr, deg, (const float*)cnt_rd,
                                         hw, b_rgcn, h2, n);
  }
  // 11. qkvs = h2 @ Wqkvs + bqkvs
  {
    dim3 g((n + 63) / 64, 128 / 64);
    gemm_tile<true><<<g, 256, 0, stream>>>(h2, Wqkvs, bqkvs, qkvs, n, H2D, 128);
  }
  // 12. attention + skip + relu + classifier -> out
  {
    int blocks = (n * 64 + 255) / 256;
    attn_out<<<blocks, 256, 0, stream>>>(csr, rowptr, deg, qkvs, bskip, Wf, bf,
                                         out, n);
  }
}

// Round 8
// 1245.241 us; speedup vs baseline: 1.2117x; 1.2117x over previous
//
#include <hip/hip_runtime.h>
#include <hip/hip_bf16.h>
#include <math.h>

// N=100000, E=3200000, R=9, G=768, H1=64, H2=32, C=4
// Pipeline:
//   h1 = x@Wp + bp                                  [N,64]
//   hw = h1 @ [W_rel(9) | W_root] (concat cols)     [N,320]
//   2-level bucketed CSR build (bucket = dst>>10, 98 buckets)
//   h2 = relu( sum_e hw[src][r]/cnt(r,dst) + hw[dst][root] + b_rgcn )
//   qkvs = h2 @ [Wq|Wk|Wv|Wskip] + biases           [N,128]
//   per-dst online softmax attn; h3 = relu(attn + skip); out = h3@Wf+bf fused

#define GDIM 768
#define H1D 64
#define H2D 32
#define NREL 9
#define NBK 98         // ceil(100000/1024)
#define BKT_SHIFT 10
#define CHUNK 8192

// record packing: (dstLow:10)<<21 | (type:4)<<17 | (src:17)
#define SRC_MASK 0x1FFFFu
#define PAY_MASK 0x1FFFFFu

// ---------------- small utility kernels ----------------

__global__ void zero_ints(int* __restrict__ p, int count) {
  for (int i = blockIdx.x * blockDim.x + threadIdx.x; i < count;
       i += gridDim.x * blockDim.x)
    p[i] = 0;
}

__global__ void build_wcat(const float* __restrict__ W_rel,
                           const float* __restrict__ W_root,
                           float* __restrict__ Wcat) {
  int i = blockIdx.x * blockDim.x + threadIdx.x;
  if (i >= H1D * 320) return;
  int k = i / 320, m = i % 320;
  float v;
  if (m < NREL * H2D) {
    int r = m >> 5, o = m & 31;
    v = W_rel[(size_t)r * H1D * H2D + k * H2D + o];
  } else {
    v = W_root[k * H2D + (m - NREL * H2D)];
  }
  Wcat[i] = v;
}

__global__ void build_wqkvs(const float* __restrict__ Wq, const float* __restrict__ Wk,
                            const float* __restrict__ Wv, const float* __restrict__ Ws,
                            const float* __restrict__ bq, const float* __restrict__ bk,
                            const float* __restrict__ bv, const float* __restrict__ bs,
                            float* __restrict__ Wqkvs, float* __restrict__ bqkvs) {
  int i = blockIdx.x * blockDim.x + threadIdx.x;
  if (i < H2D * 128) {
    int k = i / 128, c = i % 128;
    int sel = c >> 5, o = c & 31;
    const float* W = (sel == 0) ? Wq : (sel == 1) ? Wk : (sel == 2) ? Wv : Ws;
    Wqkvs[i] = W[k * H2D + o];
  }
  if (i < 128) {
    int sel = i >> 5, o = i & 31;
    const float* b = (sel == 0) ? bq : (sel == 1) ? bk : (sel == 2) ? bv : bs;
    bqkvs[i] = b[o];
  }
}

// ---------------- generic fp32 tiled GEMM: C = A[MxK] @ B[KxN] (+bias) ----------------

template <bool BIAS>
__global__ __launch_bounds__(256) void gemm_tile(
    const float* __restrict__ A, const float* __restrict__ B,
    const float* __restrict__ bias, float* __restrict__ C, int M, int K, int N) {
  __shared__ float As[64][17];
  __shared__ float Bs[16][68];
  const int m0 = blockIdx.x * 64;
  const int n0 = blockIdx.y * 64;
  const int tid = threadIdx.x;
  const int tr = tid >> 4, tc = tid & 15;

  float acc[4][4] = {{0.f}};

  for (int kk = 0; kk < K; kk += 16) {
    {
      int ar = tid >> 2;
      int ac = (tid & 3) * 4;
      float4 av = make_float4(0.f, 0.f, 0.f, 0.f);
      if (m0 + ar < M)
        av = *(const float4*)(A + (size_t)(m0 + ar) * K + kk + ac);
      As[ar][ac + 0] = av.x; As[ar][ac + 1] = av.y;
      As[ar][ac + 2] = av.z; As[ar][ac + 3] = av.w;
    }
    {
      int br = tid >> 4;
      int bc = (tid & 15) * 4;
      float4 bv = *(const float4*)(B + (size_t)(kk + br) * N + n0 + bc);
      *(float4*)(&Bs[br][bc]) = bv;
    }
    __syncthreads();
#pragma unroll
    for (int k = 0; k < 16; ++k) {
      float a0 = As[tr * 4 + 0][k];
      float a1 = As[tr * 4 + 1][k];
      float a2 = As[tr * 4 + 2][k];
      float a3 = As[tr * 4 + 3][k];
      float4 b = *(const float4*)(&Bs[k][tc * 4]);
      acc[0][0] += a0 * b.x; acc[0][1] += a0 * b.y; acc[0][2] += a0 * b.z; acc[0][3] += a0 * b.w;
      acc[1][0] += a1 * b.x; acc[1][1] += a1 * b.y; acc[1][2] += a1 * b.z; acc[1][3] += a1 * b.w;
      acc[2][0] += a2 * b.x; acc[2][1] += a2 * b.y; acc[2][2] += a2 * b.z; acc[2][3] += a2 * b.w;
      acc[3][0] += a3 * b.x; acc[3][1] += a3 * b.y; acc[3][2] += a3 * b.z; acc[3][3] += a3 * b.w;
    }
    __syncthreads();
  }

#pragma unroll
  for (int i = 0; i < 4; ++i) {
    int row = m0 + tr * 4 + i;
    if (row < M) {
      int col = n0 + tc * 4;
      float4 v;
      v.x = acc[i][0]; v.y = acc[i][1]; v.z = acc[i][2]; v.w = acc[i][3];
      if (BIAS) {
        v.x += bias[col + 0]; v.y += bias[col + 1];
        v.z += bias[col + 2]; v.w += bias[col + 3];
      }
      *(float4*)(C + (size_t)row * N + col) = v;
    }
  }
}

// ---------------- 2-level bucketed CSR build ----------------

__global__ void bucket_count(const int* __restrict__ ei, int* __restrict__ bucketCnt,
                             int e) {
  __shared__ int h[NBK];
  for (int t = threadIdx.x; t < NBK; t += 256) h[t] = 0;
  __syncthreads();
  for (int i = blockIdx.x * 256 + threadIdx.x; i < e; i += gridDim.x * 256)
    atomicAdd(&h[ei[e + i] >> BKT_SHIFT], 1);
  __syncthreads();
  for (int t = threadIdx.x; t < NBK; t += 256) atomicAdd(&bucketCnt[t], h[t]);
}

// single block, 128 threads: exclusive scan of 98 bucket counts
__global__ void scan_buckets(const int* __restrict__ bucketCnt,
                             int* __restrict__ bucketBase,
                             int* __restrict__ bucketCursor) {
  __shared__ int s[128];
  int t = threadIdx.x;
  int v = (t < NBK) ? bucketCnt[t] : 0;
  s[t] = v;
  __syncthreads();
  for (int off = 1; off < 128; off <<= 1) {
    int add = (t >= off) ? s[t - off] : 0;
    __syncthreads();
    s[t] += add;
    __syncthreads();
  }
  if (t < NBK) {
    int ex = s[t] - v;
    bucketBase[t] = ex;
    bucketCursor[t] = ex;
  }
}

// bin edges into bucket-grouped 4B records (per-block LDS hist + run reservation)
__global__ __launch_bounds__(256) void bin_scatter(const int* __restrict__ ei,
                                                   const int* __restrict__ et,
                                                   int* __restrict__ bucketCursor,
                                                   unsigned* __restrict__ binned,
                                                   int e) {
  __shared__ int h[NBK];
  __shared__ int rb[NBK];
  int cb = blockIdx.x * CHUNK;
  int cnt = min(CHUNK, e - cb);
  for (int t = threadIdx.x; t < NBK; t += 256) h[t] = 0;
  __syncthreads();
  for (int j = threadIdx.x; j < cnt; j += 256)
    atomicAdd(&h[ei[e + cb + j] >> BKT_SHIFT], 1);
  __syncthreads();
  for (int t = threadIdx.x; t < NBK; t += 256)
    rb[t] = atomicAdd(&bucketCursor[t], h[t]);
  __syncthreads();
  for (int t = threadIdx.x; t < NBK; t += 256) h[t] = 0;
  __syncthreads();
  for (int j = threadIdx.x; j < cnt; j += 256) {
    int dst = ei[e + cb + j];
    int b = dst >> BKT_SHIFT;
    unsigned rec = ((unsigned)(dst & 1023) << 21) |
                   ((unsigned)et[cb + j] << 17) | (unsigned)ei[cb + j];
    int lp = atomicAdd(&h[b], 1);
    binned[rb[b] + lp] = rec;
  }
}

// per-bucket dst histogram -> deg  (4 blocks per bucket)
__global__ __launch_bounds__(256) void deg_hist(const unsigned* __restrict__ binned,
                                                const int* __restrict__ bucketBase,
                                                const int* __restrict__ bucketCnt,
                                                int* __restrict__ deg, int n) {
  __shared__ int d[1024];
  int bkt = blockIdx.x >> 2, part = blockIdx.x & 3;
  for (int t = threadIdx.x; t < 1024; t += 256) d[t] = 0;
  __syncthreads();
  int base = bucketBase[bkt], bc = bucketCnt[bkt];
  int q = (bc + 3) >> 2;
  int s0 = part * q, s1 = min(s0 + q, bc);
  for (int j = s0 + threadIdx.x; j < s1; j += 256)
    atomicAdd(&d[binned[base + j] >> 21], 1);
  __syncthreads();
  int d0 = bkt << BKT_SHIFT;
  for (int t = threadIdx.x; t < 1024; t += 256) {
    int dst = d0 + t;
    if (dst < n && d[t]) atomicAdd(&deg[dst], d[t]);
  }
}

__global__ void scan_block_sums(const int* __restrict__ deg, int* __restrict__ partials,
                                int n) {
  int i = blockIdx.x * 256 + threadIdx.x;
  int v = (i < n) ? deg[i] : 0;
#pragma unroll
  for (int off = 32; off > 0; off >>= 1) v += __shfl_down(v, off, 64);
  __shared__ int wsum[4];
  if ((threadIdx.x & 63) == 0) wsum[threadIdx.x >> 6] = v;
  __syncthreads();
  if (threadIdx.x == 0)
    partials[blockIdx.x] = wsum[0] + wsum[1] + wsum[2] + wsum[3];
}

__global__ void scan_partials(const int* __restrict__ partials,
                              int* __restrict__ blockoff, int nb) {
  __shared__ int s[1024];
  int t = threadIdx.x;
  int v = (t < nb) ? partials[t] : 0;
  s[t] = v;
  __syncthreads();
  for (int off = 1; off < 1024; off <<= 1) {
    int add = (t >= off) ? s[t - off] : 0;
    __syncthreads();
    s[t] += add;
    __syncthreads();
  }
  blockoff[t] = s[t] - v;  // exclusive
}

__global__ void scan_final(const int* __restrict__ deg, const int* __restrict__ blockoff,
                           int* __restrict__ rowptr, int* __restrict__ cursor, int n) {
  int i = blockIdx.x * 256 + threadIdx.x;
  int lane = threadIdx.x & 63;
  int v = (i < n) ? deg[i] : 0;
  int incl = v;
#pragma unroll
  for (int off = 1; off < 64; off <<= 1) {
    int u = __shfl_up(incl, off, 64);
    if (lane >= off) incl += u;
  }
  __shared__ int wsum[4];
  if (lane == 63) wsum[threadIdx.x >> 6] = incl;
  __syncthreads();
  int w = threadIdx.x >> 6;
  int woff = 0;
  for (int j = 0; j < w; ++j) woff += wsum[j];
  int excl = incl - v + woff + blockoff[blockIdx.x];
  if (i < n) {
    rowptr[i] = excl;
    cursor[i] = excl;
  }
}

// final per-dst scatter; all traffic L2-localized per bucket  (4 blocks per bucket)
__global__ __launch_bounds__(256) void csr_scatter(const unsigned* __restrict__ binned,
                                                   const int* __restrict__ bucketBase,
                                                   const int* __restrict__ bucketCnt,
                                                   int* __restrict__ cursor,
                                                   unsigned* __restrict__ csr, int n) {
  int bkt = blockIdx.x >> 2, part = blockIdx.x & 3;
  int base = bucketBase[bkt], bc = bucketCnt[bkt];
  int q = (bc + 3) >> 2;
  int s0 = part * q, s1 = min(s0 + q, bc);
  int d0 = bkt << BKT_SHIFT;
  for (int j = s0 + threadIdx.x; j < s1; j += 256) {
    unsigned rec = binned[base + j];
    int dst = d0 + (int)(rec >> 21);
    int pos = atomicAdd(&cursor[dst], 1);
    csr[pos] = rec & PAY_MASK;
  }
}

// ---------------- RGCN aggregate: one wave per dst ----------------
// pass 1: per-relation edge counts (lane o counts type==o); pass 2: weighted sum.

__global__ __launch_bounds__(256) void rgcn_agg(
    const unsigned* __restrict__ csr, const int* __restrict__ rowptr,
    const int* __restrict__ deg, const float* __restrict__ hw,
    const float* __restrict__ b_rgcn, float* __restrict__ h2, int n) {
  int wid = (blockIdx.x * 256 + threadIdx.x) >> 6;
  if (wid >= n) return;
  int lane = threadIdx.x & 63;
  int half = lane >> 5, o = lane & 31;
  int start = rowptr[wid];
  int cnt = deg[wid];

  int rc = 0;
  for (int i = half; i < cnt; i += 2) {
    unsigned p = csr[start + i];
    int r = (p >> 17) & 0xF;
    rc += (r == o) ? 1 : 0;
  }
  rc += __shfl_xor(rc, 32, 64);
  float inv = 1.0f / (float)max(rc, 1);

  float acc = 0.f;
  for (int i = half; i < cnt; i += 2) {
    unsigned p = csr[start + i];
    int src = p & SRC_MASK;
    int r = (p >> 17) & 0xF;
    float norm = __shfl(inv, r, 32);
    acc += hw[(size_t)src * 320 + r * 32 + o] * norm;
  }
  acc += __shfl_xor(acc, 32, 64);
  float root = hw[(size_t)wid * 320 + NREL * 32 + o] + b_rgcn[o];
  float v = acc + root;
  v = v > 0.f ? v : 0.f;
  if (half == 0) h2[(size_t)wid * 32 + o] = v;
}

// ---------------- attention + skip + classifier: one wave per dst ----------------

__global__ __launch_bounds__(256) void attn_out(
    const unsigned* __restrict__ csr, const int* __restrict__ rowptr,
    const int* __restrict__ deg, const float* __restrict__ qkvs,
    const float* __restrict__ bskip, const float* __restrict__ Wf,
    const float* __restrict__ bf, float* __restrict__ out, int n) {
  int wid = (blockIdx.x * 256 + threadIdx.x) >> 6;
  if (wid >= n) return;
  int lane = threadIdx.x & 63;
  int half = lane >> 5, o = lane & 31;
  const float scale = 0.1767766952966369f;  // 1/sqrt(32)

  float qv = qkvs[(size_t)wid * 128 + o];
  int start = rowptr[wid];
  int cnt = deg[wid];

  float m = -INFINITY, den = 0.f, acc = 0.f;
  for (int i = half; i < cnt; i += 2) {
    unsigned p = csr[start + i];
    int src = p & SRC_MASK;
    float kv = qkvs[(size_t)src * 128 + 32 + o];
    float vv = qkvs[(size_t)src * 128 + 64 + o];
    float prod = qv * kv;
    prod += __shfl_xor(prod, 1, 64);
    prod += __shfl_xor(prod, 2, 64);
    prod += __shfl_xor(prod, 4, 64);
    prod += __shfl_xor(prod, 8, 64);
    prod += __shfl_xor(prod, 16, 64);
    float logit = prod * scale;
    float nm = fmaxf(m, logit);
    float c = __expf(m - nm);
    float pp = __expf(logit - nm);
    den = den * c + pp;
    acc = acc * c + pp * vv;
    m = nm;
  }
  float mo = __shfl_xor(m, 32, 64);
  float nm = fmaxf(m, mo);
  float c = (m > -INFINITY) ? __expf(m - nm) : 0.f;
  float sden = den * c, sacc = acc * c;
  sden += __shfl_xor(sden, 32, 64);
  sacc += __shfl_xor(sacc, 32, 64);
  float attn = (sden > 0.f) ? (sacc / sden) : 0.f;

  float sv = qkvs[(size_t)wid * 128 + 96 + o] + bskip[o];
  float h3 = attn + sv;
  h3 = h3 > 0.f ? h3 : 0.f;

#pragma unroll
  for (int cidx = 0; cidx < 4; ++cidx) {
    float t = h3 * Wf[o * 4 + cidx];
    t += __shfl_xor(t, 1, 64);
    t += __shfl_xor(t, 2, 64);
    t += __shfl_xor(t, 4, 64);
    t += __shfl_xor(t, 8, 64);
    t += __shfl_xor(t, 16, 64);
    if (lane == 0) out[(size_t)wid * 4 + cidx] = t + bf[cidx];
  }
}

// ---------------- launch ----------------

extern "C" void kernel_launch(void* const* d_in, const int* in_sizes, int n_in,
                              void* d_out, int out_size, void* d_ws, size_t ws_size,
                              hipStream_t stream) {
  const float* x      = (const float*)d_in[0];
  const int*   ei     = (const int*)d_in[2];
  const int*   et     = (const int*)d_in[3];
  const float* Wp     = (const float*)d_in[4];
  const float* bp     = (const float*)d_in[5];
  const float* W_rel  = (const float*)d_in[6];
  const float* W_root = (const float*)d_in[7];
  const float* b_rgcn = (const float*)d_in[8];
  const float* Wq     = (const float*)d_in[9];
  const float* bq     = (const float*)d_in[10];
  const float* Wk     = (const float*)d_in[11];
  const float* bk     = (const float*)d_in[12];
  const float* Wv     = (const float*)d_in[13];
  const float* bv     = (const float*)d_in[14];
  const float* Wskip  = (const float*)d_in[15];
  const float* bskip  = (const float*)d_in[16];
  const float* Wf     = (const float*)d_in[17];
  const float* bf     = (const float*)d_in[18];
  float* out = (float*)d_out;

  const int n = in_sizes[0] / GDIM;      // 100000
  const int e = in_sizes[3];             // 3200000

  // workspace layout (floats)
  float* ws = (float*)d_ws;
  size_t off = 0;
  float* h1    = ws + off; off += (size_t)n * H1D;        // 6.4M floats (aliased by binned)
  float* hw    = ws + off; off += (size_t)n * 320;
  float* h2    = ws + off; off += (size_t)n * H2D;
  float* qkvs  = ws + off; off += (size_t)n * 128;
  float* Wcat  = ws + off; off += (size_t)H1D * 320;
  float* Wqkvs = ws + off; off += (size_t)H2D * 128;
  float* bqkvs = ws + off; off += 128;
  int* deg     = (int*)(ws + off); off += n;
  int* bucketCnt    = (int*)(ws + off); off += NBK;       // zeroed together with deg
  int* bucketBase   = (int*)(ws + off); off += NBK;
  int* bucketCursor = (int*)(ws + off); off += NBK;
  int* rowptr  = (int*)(ws + off); off += n;
  int* cursor  = (int*)(ws + off); off += n;
  int* partials= (int*)(ws + off); off += 1024;
  int* blockoff= (int*)(ws + off); off += 1024;
  unsigned* csr= (unsigned*)(ws + off); off += e;
  unsigned* binned = (unsigned*)h1;   // h1 is dead once hw is computed

  const int nb = (n + 255) / 256;           // 391
  const int nchunks = (e + CHUNK - 1) / CHUNK;  // 391

  // 1. zero deg + bucketCnt (contiguous)
  zero_ints<<<1024, 256, 0, stream>>>(deg, n + NBK);
  // 2. weights
  build_wcat<<<(H1D * 320 + 255) / 256, 256, 0, stream>>>(W_rel, W_root, Wcat);
  build_wqkvs<<<(H2D * 128 + 255) / 256, 256, 0, stream>>>(
      Wq, Wk, Wv, Wskip, bq, bk, bv, bskip, Wqkvs, bqkvs);
  // 3. h1 = x@Wp + bp
  {
    dim3 g((n + 63) / 64, H1D / 64);
    gemm_tile<true><<<g, 256, 0, stream>>>(x, Wp, bp, h1, n, GDIM, H1D);
  }
  // 4. hw = h1 @ Wcat  (h1 dead afterwards)
  {
    dim3 g((n + 63) / 64, 320 / 64);
    gemm_tile<false><<<g, 256, 0, stream>>>(h1, Wcat, nullptr, hw, n, H1D, 320);
  }
  // 5. bucketed CSR build
  bucket_count<<<256, 256, 0, stream>>>(ei, bucketCnt, e);
  scan_buckets<<<1, 128, 0, stream>>>(bucketCnt, bucketBase, bucketCursor);
  bin_scatter<<<nchunks, 256, 0, stream>>>(ei, et, bucketCursor, binned, e);
  deg_hist<<<NBK * 4, 256, 0, stream>>>(binned, bucketBase, bucketCnt, deg, n);
  scan_block_sums<<<nb, 256, 0, stream>>>(deg, partials, n);
  scan_partials<<<1, 1024, 0, stream>>>(partials, blockoff, nb);
  scan_final<<<nb, 256, 0, stream>>>(deg, blockoff, rowptr, cursor, n);
  csr_scatter<<<NBK * 4, 256, 0, stream>>>(binned, bucketBase, bucketCnt, cursor, csr, n);
  // 6. RGCN aggregate -> h2
  {
    int blocks = (n * 64 + 255) / 256;
    rgcn_agg<<<blocks, 256, 0, stream>>>(csr, rowptr, deg, hw, b_rgcn, h2, n);
  }
  // 7. qkvs = h2 @ Wqkvs + bqkvs
  {
    dim3 g((n + 63) / 64, 128 / 64);
    gemm_tile<true><<<g, 256, 0, stream>>>(h2, Wqkvs, bqkvs, qkvs, n, H2D, 128);
  }
  // 8. attention + skip + relu + classifier -> out
  {
    int blocks = (n * 64 + 255) / 256;
    attn_out<<<blocks, 256, 0, stream>>>(csr, rowptr, deg, qkvs, bskip, Wf, bf,
                                         out, n);
  }
}